// Round 7
// baseline (554.830 us; speedup 1.0000x reference)
//
#include <hip/hip_runtime.h>

#define BB 8
#define NN 128
#define ND 64
#define LL 512
#define RD 1024
#define CG 128
#define CP 128
#define HID 192

typedef __attribute__((ext_vector_type(8))) short short8;
typedef __attribute__((ext_vector_type(4))) float f32x4;

__device__ __forceinline__ unsigned short f2bf(float x) {
    unsigned u = __builtin_bit_cast(unsigned, x);
    u += 0x7fffu + ((u >> 16) & 1u);          // RNE
    return (unsigned short)(u >> 16);
}

// ---------------------------------------------------------------------------
// K1 (grid 2561 x 256):
//  blk <256   : h0 = nodes@Wn + bn ; norm = rsqrt(max(deg,1))
//  blk ==256  : vbuf = W2@Wo ; b1c = b1 + br@W1b ; cconst ; acc=0; ctr=0
//  257..512   : WcT[c][k] = bf16( (Wr@W1b)[k][c] )   (4 k-rows per block)
//  513..2560  : protb = bf16(prot)  (2048 elems per block)
// ---------------------------------------------------------------------------
__global__ __launch_bounds__(256) void k1_prep(
    const float* __restrict__ adj, const float* __restrict__ nodes,
    const float* __restrict__ prot,
    const float* __restrict__ Wn, const float* __restrict__ bn,
    const float* __restrict__ Wr, const float* __restrict__ br,
    const float* __restrict__ W1, const float* __restrict__ b1,
    const float* __restrict__ W2, const float* __restrict__ b2,
    const float* __restrict__ Wo, const float* __restrict__ bo,
    float* __restrict__ hA, float* __restrict__ normb,
    float* __restrict__ vbuf, float* __restrict__ cconst,
    float* __restrict__ acc, unsigned* __restrict__ ctr,
    unsigned short* __restrict__ WcT, float* __restrict__ b1c,
    unsigned short* __restrict__ protb)
{
    int t = threadIdx.x;
    int blk = blockIdx.x;
    const float* W1b = W1 + CG * HID;
    if (blk >= 513) {
        size_t base = (size_t)(blk - 513) * 2048 + (size_t)t * 8;
        float4 p0 = *(const float4*)(prot + base);
        float4 p1 = *(const float4*)(prot + base + 4);
        unsigned short o[8];
        o[0] = f2bf(p0.x); o[1] = f2bf(p0.y); o[2] = f2bf(p0.z); o[3] = f2bf(p0.w);
        o[4] = f2bf(p1.x); o[5] = f2bf(p1.y); o[6] = f2bf(p1.z); o[7] = f2bf(p1.w);
        *(short8*)(protb + base) = *(const short8*)o;
        return;
    }
    if (blk == 256) {
        if (t < HID) {
            float s = 0.f;
            for (int k = 0; k < CG; ++k) s = fmaf(W2[t * CG + k], Wo[k], s);
            vbuf[t] = s;
            float sb = 0.f;
            for (int m = 0; m < CG; ++m) sb = fmaf(br[m], W1b[m * HID + t], sb);
            b1c[t] = b1[t] + sb;
        }
        if (t == 255) {
            float s = 0.f;
            for (int k = 0; k < CG; ++k) s = fmaf(b2[k], Wo[k], s);
            cconst[0] = (float)(NN * LL) * s + bo[0];
        }
        if (t == 254) *ctr = 0u;
        if (t < BB) acc[t] = 0.f;
        return;
    }
    if (blk > 256) {
        int r0 = (blk - 257) * 4;
        __shared__ float sW[4][CG];
        if (t < 128) ((float4*)&sW[0][0])[t] = ((const float4*)(Wr + (size_t)r0 * CG))[t];
        __syncthreads();
        #pragma unroll
        for (int q = 0; q < 3; ++q) {
            int o = q * 256 + t;            // 0..767
            int r = o / HID, c = o % HID;
            float s = 0.f;
            for (int m = 0; m < CG; ++m) s = fmaf(sW[r][m], W1b[m * HID + c], s);
            WcT[(size_t)c * RD + r0 + r] = f2bf(s);
        }
        return;
    }
    int b = blk >> 5;           // 32 blocks per batch
    int n0 = (blk & 31) * 4;    // 4 rows per block
    __shared__ float sn[4][ND];
    sn[t >> 6][t & 63] = nodes[(b * NN + n0 + (t >> 6)) * ND + (t & 63)];
    __syncthreads();
    {
        int w = t >> 6, lane = t & 63;
        const float* ar = adj + (size_t)(b * NN + n0 + w) * NN;
        float d = ar[lane] + ar[lane + 64];
        for (int off = 32; off; off >>= 1) d += __shfl_down(d, off);
        if (lane == 0) normb[b * NN + n0 + w] = rsqrtf(fmaxf(d, 1.0f));
    }
    int c = t & 127, rr = t >> 7;   // rows rr and rr+2
    float a0 = bn[c], a1 = bn[c];
    for (int k = 0; k < ND; ++k) {
        float wv = Wn[k * CG + c];
        a0 = fmaf(sn[rr][k], wv, a0);
        a1 = fmaf(sn[rr + 2][k], wv, a1);
    }
    hA[(b * NN + n0 + rr) * CG + c] = a0;
    hA[(b * NN + n0 + rr + 2) * CG + c] = a1;
}

// ---------------------------------------------------------------------------
// KMIX, grid 72 x 1024:
//  blocks 0..7  : whole 3-step GNN + hW1 for batch=blk, in-block syncs only.
//                 LDS: hs (scaled h, 64KB) + mm (m / tanh-h, 64KB) + norm.
//  blocks 8..71 : MFMA GEMM rW = protb @ WcT^T, full K=1024.
//                 block kb owns 64 rows x 192 cols; wave (rw,cw) 16r x 48c.
// Both halves depend only on k1 outputs -> no cross-block sync needed.
// ---------------------------------------------------------------------------
__global__ __launch_bounds__(1024) void kmix(
    const unsigned short* __restrict__ protb, const unsigned short* __restrict__ WcT,
    float* __restrict__ rW,
    const float* __restrict__ adj, const float* __restrict__ Wg,
    const float* __restrict__ bg, const float* __restrict__ normb,
    const float* __restrict__ hA,
    const float* __restrict__ W1, const float* __restrict__ b1c,
    float* __restrict__ hW1)
{
    int t = threadIdx.x;
    int blk = blockIdx.x;
    if (blk >= 8) {
        // ---------------- MFMA GEMM part ----------------
        int kb = blk - 8;            // 0..63
        int w = t >> 6;              // 0..15
        int l = t & 63;
        int rw = w & 3;              // 16-row group
        int cw = w >> 2;             // 48-col group
        int r0 = kb * 64 + rw * 16;
        int c0 = cw * 48;
        int lr = l & 15;
        int lk = (l >> 4) * 8;
        const unsigned short* ap = protb + (size_t)(r0 + lr) * RD + lk;
        const unsigned short* bp = WcT + (size_t)(c0 + lr) * RD + lk;
        f32x4 a0 = {0.f, 0.f, 0.f, 0.f}, a1 = a0, a2 = a0;
        #pragma unroll 4
        for (int k0 = 0; k0 < RD; k0 += 32) {
            short8 av = *(const short8*)(ap + k0);
            short8 b0 = *(const short8*)(bp + k0);
            short8 b1 = *(const short8*)(bp + 16 * RD + k0);
            short8 b2 = *(const short8*)(bp + 32 * RD + k0);
            a0 = __builtin_amdgcn_mfma_f32_16x16x32_bf16(av, b0, a0, 0, 0, 0);
            a1 = __builtin_amdgcn_mfma_f32_16x16x32_bf16(av, b1, a1, 0, 0, 0);
            a2 = __builtin_amdgcn_mfma_f32_16x16x32_bf16(av, b2, a2, 0, 0, 0);
        }
        int orow = r0 + (l >> 4) * 4;
        #pragma unroll
        for (int i = 0; i < 4; ++i) {
            float* cr = rW + (size_t)(orow + i) * HID + c0 + lr;
            cr[0]  = a0[i];
            cr[16] = a1[i];
            cr[32] = a2[i];
        }
        return;
    }
    // ---------------- whole-GNN part (batch = blk) ----------------
    __shared__ float hs[NN][CG];   // scaled h (h * norm), 64 KB
    __shared__ float mm[NN][CG];   // m buffer / final tanh-h, 64 KB
    __shared__ float snorm[NN];
    int b = blk;
    int c = t & 127;
    int ig = t >> 7;               // 0..7 (wave-uniform)
    if (t < NN) snorm[t] = normb[b * NN + t];
    __syncthreads();
    // stage hs = hA[b] * snorm  (4096 float4 / 1024 thr = 4 each)
    #pragma unroll
    for (int q = 0; q < 4; ++q) {
        int f4 = t + 1024 * q;         // 0..4095
        int row = f4 >> 5;             // 0..127
        int col4 = (f4 & 31) * 4;
        float4 hv = *(const float4*)(hA + ((size_t)b * NN + row) * CG + col4);
        float nv = snorm[row];
        hv.x *= nv; hv.y *= nv; hv.z *= nv; hv.w *= nv;
        *(float4*)(&hs[row][col4]) = hv;
    }
    __syncthreads();
    for (int s = 0; s < 3; ++s) {
        // m phase: thread owns rows i = ig + 8r (16 rows), col c
        float macc[16];
        #pragma unroll
        for (int r = 0; r < 16; ++r) macc[r] = 0.f;
        const float* abase = adj + ((size_t)b * NN + ig) * NN;   // wave-uniform
        for (int j = 0; j < NN; ++j) {
            float hv = hs[j][c];
            #pragma unroll
            for (int r = 0; r < 16; ++r)
                macc[r] = fmaf(abase[(size_t)r * 8 * NN + j], hv, macc[r]);
        }
        #pragma unroll
        for (int r = 0; r < 16; ++r) {
            int i = ig + r * 8;
            mm[i][c] = macc[r] * snorm[i];
        }
        __syncthreads();
        // hnew phase: hnew[i][c] = act( mm[i][:] @ Wg[:, c] + bg[c] )
        float hacc[16];
        #pragma unroll
        for (int r = 0; r < 16; ++r) hacc[r] = bg[c];
        for (int k = 0; k < CG; ++k) {
            float wgv = Wg[k * CG + c];
            #pragma unroll
            for (int r = 0; r < 16; ++r)
                hacc[r] = fmaf(mm[ig + r * 8][k], wgv, hacc[r]);
        }
        __syncthreads();   // all mm reads done before hs overwrite
        if (s < 2) {
            #pragma unroll
            for (int r = 0; r < 16; ++r) {
                int i = ig + r * 8;
                hs[i][c] = fmaxf(hacc[r], 0.f) * snorm[i];   // keep scaled
            }
        } else {
            #pragma unroll
            for (int r = 0; r < 16; ++r) {
                int i = ig + r * 8;
                hs[i][c] = tanhf(hacc[r]);                   // unscaled final
            }
        }
        __syncthreads();
    }
    // hW1 = tanh-h @ W1_top + b1c : 128*192 outputs, 24 per thread
    #pragma unroll
    for (int q = 0; q < 24; ++q) {
        int o = t + 1024 * q;          // 0..24575
        int i = o / HID, jj = o % HID;
        float a = b1c[jj];
        for (int k = 0; k < CG; ++k)
            a = fmaf(hs[i][k], W1[k * HID + jj], a);
        hW1[((size_t)b * NN + i) * HID + jj] = a;
    }
}

// ---------------------------------------------------------------------------
// K4: acc[b] += sum_{n,l} v . relu(hW1[b,n,:] + rW[b,l,:])
//     last block writes out[b] = acc[b] + cconst.
// grid B*8(nsplit)*8(ltile) = 512 x 256
// ---------------------------------------------------------------------------
__global__ __launch_bounds__(256) void k4_pairsum(
    const float* __restrict__ hW1, const float* __restrict__ rW,
    const float* __restrict__ vbuf, float* __restrict__ acc,
    const float* __restrict__ cconst, unsigned* __restrict__ ctr,
    float* __restrict__ out)
{
    int t = threadIdx.x;
    int blk = blockIdx.x;
    int b = blk >> 6;
    int ns = (blk >> 3) & 7;    // 16-row n range
    int lt = blk & 7;           // 64-wide l tile
    int wv = t >> 6;            // j-quarter (48 dims)
    int lane = t & 63;
    int j0 = wv * 48;
    int l = lt * 64 + lane;
    float r[48], v[48];
    const float* rp = rW + ((size_t)b * LL + l) * HID + j0;
    const float* vp = vbuf + j0;
    #pragma unroll
    for (int q = 0; q < 12; ++q) {
        float4 f = *(const float4*)(rp + q * 4);
        r[q * 4 + 0] = f.x; r[q * 4 + 1] = f.y; r[q * 4 + 2] = f.z; r[q * 4 + 3] = f.w;
    }
    #pragma unroll
    for (int q = 0; q < 12; ++q) {
        float4 f = *(const float4*)(vp + q * 4);
        v[q * 4 + 0] = f.x; v[q * 4 + 1] = f.y; v[q * 4 + 2] = f.z; v[q * 4 + 3] = f.w;
    }
    float a0 = 0.f, a1 = 0.f, a2 = 0.f, a3 = 0.f;
    const float* hp = hW1 + ((size_t)b * NN + ns * 16) * HID + j0;
    for (int n = 0; n < 16; ++n) {
        float hv[48];
        #pragma unroll
        for (int q = 0; q < 12; ++q) {
            float4 f = *(const float4*)(hp + n * HID + q * 4);
            hv[q * 4 + 0] = f.x; hv[q * 4 + 1] = f.y; hv[q * 4 + 2] = f.z; hv[q * 4 + 3] = f.w;
        }
        #pragma unroll
        for (int j = 0; j < 48; j += 4) {
            a0 = fmaf(v[j + 0], fmaxf(hv[j + 0] + r[j + 0], 0.f), a0);
            a1 = fmaf(v[j + 1], fmaxf(hv[j + 1] + r[j + 1], 0.f), a1);
            a2 = fmaf(v[j + 2], fmaxf(hv[j + 2] + r[j + 2], 0.f), a2);
            a3 = fmaf(v[j + 3], fmaxf(hv[j + 3] + r[j + 3], 0.f), a3);
        }
    }
    float a = (a0 + a1) + (a2 + a3);
    for (int off = 32; off; off >>= 1) a += __shfl_down(a, off);
    __shared__ float sred[4];
    __shared__ int lastf;
    if (lane == 0) sred[wv] = a;
    __syncthreads();
    if (t == 0) {
        atomicAdd(&acc[b], (sred[0] + sred[1]) + (sred[2] + sred[3]));
        __threadfence();
        unsigned old = atomicAdd(ctr, 1u);
        lastf = (old == gridDim.x - 1) ? 1 : 0;
    }
    __syncthreads();
    if (lastf && t < BB)
        out[t] = atomicAdd(&acc[t], 0.0f) + cconst[0];
}

extern "C" void kernel_launch(void* const* d_in, const int* in_sizes, int n_in,
                              void* d_out, int out_size, void* d_ws, size_t ws_size,
                              hipStream_t stream)
{
    const float* adj   = (const float*)d_in[0];
    const float* nodes = (const float*)d_in[1];
    const float* prot  = (const float*)d_in[2];
    const float* Wn    = (const float*)d_in[3];
    const float* bn    = (const float*)d_in[4];
    const float* Wg    = (const float*)d_in[5];
    const float* bg    = (const float*)d_in[6];
    const float* Wr    = (const float*)d_in[7];
    const float* br    = (const float*)d_in[8];
    // d_in[9]=Wa, d_in[10]=ba: unused (softmax over size-1 axis == 1)
    const float* W1    = (const float*)d_in[11];
    const float* b1    = (const float*)d_in[12];
    const float* W2    = (const float*)d_in[13];
    const float* b2    = (const float*)d_in[14];
    const float* Wo    = (const float*)d_in[15];
    const float* bo    = (const float*)d_in[16];

    float* ws     = (float*)d_ws;
    float* hA     = ws;                        // [8][128][128]
    float* normb  = ws + 131072;               // [8][128]
    float* hW1b   = ws + 132096;               // [8][128][192]
    float* rW     = ws + 328704;               // [4096][192]
    float* vbuf   = ws + 1115136;              // [192]
    float* cconst = ws + 1115328;              // [1]
    float* accb   = ws + 1115332;              // [8]
    float* b1c    = ws + 1115340;              // [192]
    unsigned* ctr = (unsigned*)(ws + 1115532); // [1]
    unsigned short* protb = (unsigned short*)(ws + 1115536); // [4096][1024] bf16
    unsigned short* WcT   = (unsigned short*)(ws + 3212688); // [192][1024] bf16
    float* out    = (float*)d_out;

    hipLaunchKernelGGL(k1_prep, dim3(2561), dim3(256), 0, stream,
                       adj, nodes, prot, Wn, bn, Wr, br, W1, b1, W2, b2, Wo, bo,
                       hA, normb, vbuf, cconst, accb, ctr, WcT, b1c, protb);
    hipLaunchKernelGGL(kmix, dim3(72), dim3(1024), 0, stream,
                       protb, WcT, rW, adj, Wg, bg, normb, hA, W1, b1c, hW1b);
    hipLaunchKernelGGL(k4_pairsum, dim3(512), dim3(256), 0, stream,
                       hW1b, rW, vbuf, accb, cconst, ctr, out);
}

// Round 8
// 88.389 us; speedup vs baseline: 6.2772x; 6.2772x over previous
//
#include <hip/hip_runtime.h>

#define BB 8
#define NN 128
#define ND 64
#define LL 512
#define RD 1024
#define CG 128
#define CP 128
#define HID 192

typedef __attribute__((ext_vector_type(8))) short short8;
typedef __attribute__((ext_vector_type(4))) float f32x4;

__device__ __forceinline__ unsigned short f2bf(float x) {
    unsigned u = __builtin_bit_cast(unsigned, x);
    u += 0x7fffu + ((u >> 16) & 1u);          // RNE
    return (unsigned short)(u >> 16);
}

// ---------------------------------------------------------------------------
// K1 (grid 2563 x 256):
//  blk <256   : h0 = nodes@Wn + bn ; norm ; adjb = bf16(adj) (4 rows)
//  blk ==256  : vbuf = W2@Wo ; b1c = b1 + br@W1b ; cconst ; acc=0; ctr=0
//  257..512   : WcT[c][k] = bf16( (Wr@W1b)[k][c] )
//  513        : WgT[c][j] = bf16(Wg[j][c])
//  514        : W1tT[jj][k] = bf16(W1[k][jj])   (top half of W1)
//  515..2562  : protb = bf16(prot)
// ---------------------------------------------------------------------------
__global__ __launch_bounds__(256) void k1_prep(
    const float* __restrict__ adj, const float* __restrict__ nodes,
    const float* __restrict__ prot,
    const float* __restrict__ Wn, const float* __restrict__ bn,
    const float* __restrict__ Wr, const float* __restrict__ br,
    const float* __restrict__ W1, const float* __restrict__ b1,
    const float* __restrict__ Wg,
    const float* __restrict__ W2, const float* __restrict__ b2,
    const float* __restrict__ Wo, const float* __restrict__ bo,
    float* __restrict__ hA, float* __restrict__ normb,
    float* __restrict__ vbuf, float* __restrict__ cconst,
    float* __restrict__ acc, unsigned* __restrict__ ctr,
    unsigned short* __restrict__ WcT, float* __restrict__ b1c,
    unsigned short* __restrict__ protb, unsigned short* __restrict__ adjb,
    unsigned short* __restrict__ WgT, unsigned short* __restrict__ W1tT)
{
    int t = threadIdx.x;
    int blk = blockIdx.x;
    const float* W1b = W1 + CG * HID;
    if (blk >= 515) {
        size_t base = (size_t)(blk - 515) * 2048 + (size_t)t * 8;
        float4 p0 = *(const float4*)(prot + base);
        float4 p1 = *(const float4*)(prot + base + 4);
        unsigned short o[8];
        o[0] = f2bf(p0.x); o[1] = f2bf(p0.y); o[2] = f2bf(p0.z); o[3] = f2bf(p0.w);
        o[4] = f2bf(p1.x); o[5] = f2bf(p1.y); o[6] = f2bf(p1.z); o[7] = f2bf(p1.w);
        *(short8*)(protb + base) = *(const short8*)o;
        return;
    }
    if (blk == 514) {
        // W1tT[jj][k] = W1[k][jj], 192x128
        #pragma unroll
        for (int q = 0; q < 96; ++q) {
            int e = t + 256 * q;            // 0..24575
            int jj = e >> 7, k = e & 127;
            W1tT[e] = f2bf(W1[k * HID + jj]);
        }
        return;
    }
    if (blk == 513) {
        // WgT[c][j] = Wg[j][c], 128x128
        #pragma unroll
        for (int q = 0; q < 64; ++q) {
            int e = t + 256 * q;            // 0..16383
            int c = e >> 7, j = e & 127;
            WgT[e] = f2bf(Wg[j * CG + c]);
        }
        return;
    }
    if (blk == 256) {
        if (t < HID) {
            float s = 0.f;
            for (int k = 0; k < CG; ++k) s = fmaf(W2[t * CG + k], Wo[k], s);
            vbuf[t] = s;
            float sb = 0.f;
            for (int m = 0; m < CG; ++m) sb = fmaf(br[m], W1b[m * HID + t], sb);
            b1c[t] = b1[t] + sb;
        }
        if (t == 255) {
            float s = 0.f;
            for (int k = 0; k < CG; ++k) s = fmaf(b2[k], Wo[k], s);
            cconst[0] = (float)(NN * LL) * s + bo[0];
        }
        if (t == 254) *ctr = 0u;
        if (t < BB) acc[t] = 0.f;
        return;
    }
    if (blk > 256) {
        int r0 = (blk - 257) * 4;
        __shared__ float sW[4][CG];
        if (t < 128) ((float4*)&sW[0][0])[t] = ((const float4*)(Wr + (size_t)r0 * CG))[t];
        __syncthreads();
        #pragma unroll
        for (int q = 0; q < 3; ++q) {
            int o = q * 256 + t;            // 0..767
            int r = o / HID, c = o % HID;
            float s = 0.f;
            for (int m = 0; m < CG; ++m) s = fmaf(sW[r][m], W1b[m * HID + c], s);
            WcT[(size_t)c * RD + r0 + r] = f2bf(s);
        }
        return;
    }
    int b = blk >> 5;           // 32 blocks per batch
    int n0 = (blk & 31) * 4;    // 4 rows per block
    __shared__ float sn[4][ND];
    sn[t >> 6][t & 63] = nodes[(b * NN + n0 + (t >> 6)) * ND + (t & 63)];
    __syncthreads();
    {
        int w = t >> 6, lane = t & 63;
        const float* ar = adj + (size_t)(b * NN + n0 + w) * NN;
        float d = ar[lane] + ar[lane + 64];
        for (int off = 32; off; off >>= 1) d += __shfl_down(d, off);
        if (lane == 0) normb[b * NN + n0 + w] = rsqrtf(fmaxf(d, 1.0f));
    }
    // adjb: 4 rows x 128 = 512 elems, 2 per thread
    #pragma unroll
    for (int q = 0; q < 2; ++q) {
        int e = t + 256 * q;               // 0..511
        int row = e >> 7, col = e & 127;
        size_t ix = ((size_t)b * NN + n0 + row) * NN + col;
        adjb[ix] = f2bf(adj[ix]);
    }
    int c = t & 127, rr = t >> 7;   // rows rr and rr+2
    float a0 = bn[c], a1 = bn[c];
    for (int k = 0; k < ND; ++k) {
        float wv = Wn[k * CG + c];
        a0 = fmaf(sn[rr][k], wv, a0);
        a1 = fmaf(sn[rr + 2][k], wv, a1);
    }
    hA[(b * NN + n0 + rr) * CG + c] = a0;
    hA[(b * NN + n0 + rr + 2) * CG + c] = a1;
}

// ---------------------------------------------------------------------------
// KMID, grid 264 x 512 (8 waves/block, ~70KB LDS -> 2 blocks/CU):
//  blocks 0..7  : full 3-step GNN + hW1 for batch=blk, ALL matmuls via MFMA.
//  blocks 8..263: rW GEMM tiles: idx=(blk-8): kh=idx&1, cb=(idx>>1)&3,
//                 rb=idx>>3; block covers 128 rows x 48 cols x K-half.
// Both depend only on k1 outputs -> no cross-block sync.
// ---------------------------------------------------------------------------
#define LDT 136   // LDS row stride in bf16 elems (272B: 16B-aligned, low-conflict)
__global__ __launch_bounds__(512) void kmid(
    const unsigned short* __restrict__ protb, const unsigned short* __restrict__ WcT,
    float* __restrict__ rWp,
    const unsigned short* __restrict__ adjb, const unsigned short* __restrict__ WgT,
    const unsigned short* __restrict__ W1tT,
    const float* __restrict__ bg, const float* __restrict__ normb,
    const float* __restrict__ hA, const float* __restrict__ b1c,
    float* __restrict__ hW1)
{
    int t = threadIdx.x;
    int blk = blockIdx.x;
    __shared__ unsigned short hsT[NN][LDT];   // B^T of h*norm (j-major), 34KB
    __shared__ unsigned short ms[NN][LDT];    // m*norm / tanh-h, row-major, 34KB
    __shared__ float snorm[NN];

    if (blk >= 8) {
        // ---------------- rW GEMM ----------------
        int idx = blk - 8;
        int kh = idx & 1;
        int cb = (idx >> 1) & 3;
        int rb = idx >> 3;
        int w = t >> 6, l = t & 63;
        int r0 = rb * 128 + w * 16;
        int c0 = cb * 48;
        int lr = l & 15;
        int lk = (l >> 4) * 8;
        const unsigned short* ap = protb + (size_t)(r0 + lr) * RD + kh * 512 + lk;
        const unsigned short* bp = WcT + (size_t)(c0 + lr) * RD + kh * 512 + lk;
        f32x4 a0 = {0.f, 0.f, 0.f, 0.f}, a1 = a0, a2 = a0;
        #pragma unroll 4
        for (int k0 = 0; k0 < 512; k0 += 32) {
            short8 av = *(const short8*)(ap + k0);
            short8 b0 = *(const short8*)(bp + k0);
            short8 b1 = *(const short8*)(bp + 16 * RD + k0);
            short8 b2 = *(const short8*)(bp + 32 * RD + k0);
            a0 = __builtin_amdgcn_mfma_f32_16x16x32_bf16(av, b0, a0, 0, 0, 0);
            a1 = __builtin_amdgcn_mfma_f32_16x16x32_bf16(av, b1, a1, 0, 0, 0);
            a2 = __builtin_amdgcn_mfma_f32_16x16x32_bf16(av, b2, a2, 0, 0, 0);
        }
        int orow = r0 + (l >> 4) * 4;
        float* base = rWp + (size_t)kh * (4096 * HID);
        #pragma unroll
        for (int i = 0; i < 4; ++i) {
            float* cr = base + (size_t)(orow + i) * HID + c0 + lr;
            cr[0]  = a0[i];
            cr[16] = a1[i];
            cr[32] = a2[i];
        }
        return;
    }

    // ---------------- GNN per batch, MFMA ----------------
    int b = blk;
    int w = t >> 6, l = t & 63;
    int lr = l & 15;
    int ks = l >> 4;            // k-slot 0..3
    int lk = ks * 8;
    int i0 = w * 16;            // wave's 16 output rows
    if (t < NN) snorm[t] = normb[b * NN + t];
    __syncthreads();
    // stage hsT[j][k] = h0[k][j] * norm[k]
    #pragma unroll
    for (int q = 0; q < 8; ++q) {
        int f4 = t + 512 * q;          // 0..4095
        int k = f4 >> 5;               // 0..127
        int j0 = (f4 & 31) * 4;
        float4 hv = *(const float4*)(hA + ((size_t)b * NN + k) * CG + j0);
        float nv = snorm[k];
        hsT[j0 + 0][k] = f2bf(hv.x * nv);
        hsT[j0 + 1][k] = f2bf(hv.y * nv);
        hsT[j0 + 2][k] = f2bf(hv.z * nv);
        hsT[j0 + 3][k] = f2bf(hv.w * nv);
    }
    __syncthreads();

    for (int s = 0; s < 3; ++s) {
        // mm1: m = adjb @ hs ; ms[i][j] = m[i][j]*norm[i]  (wave-private rows)
        short8 af[4];
        #pragma unroll
        for (int kk = 0; kk < 4; ++kk)
            af[kk] = *(const short8*)(adjb + ((size_t)b * NN + i0 + lr) * NN + kk * 32 + lk);
        #pragma unroll
        for (int jt = 0; jt < 8; ++jt) {
            int j0 = jt * 16;
            f32x4 d = {0.f, 0.f, 0.f, 0.f};
            #pragma unroll
            for (int kk = 0; kk < 4; ++kk) {
                short8 bf = *(const short8*)(&hsT[j0 + lr][kk * 32 + lk]);
                d = __builtin_amdgcn_mfma_f32_16x16x32_bf16(af[kk], bf, d, 0, 0, 0);
            }
            #pragma unroll
            for (int i = 0; i < 4; ++i) {
                int ii = i0 + ks * 4 + i;
                ms[ii][j0 + lr] = f2bf(d[i] * snorm[ii]);
            }
        }
        __syncthreads();   // all hsT reads done; ms visible (private anyway)
        // mm2: h2 = ms @ Wg + bg ; act; s<2: hsT[c][i]=relu*norm ; s==2: tanh->ms
        unsigned short tp[8][4];
        #pragma unroll
        for (int ct = 0; ct < 8; ++ct) {
            int c0 = ct * 16;
            f32x4 d = {0.f, 0.f, 0.f, 0.f};
            #pragma unroll
            for (int kk = 0; kk < 4; ++kk) {
                short8 afm = *(const short8*)(&ms[i0 + lr][kk * 32 + lk]);
                short8 bfw = *(const short8*)(WgT + (size_t)(c0 + lr) * CG + kk * 32 + lk);
                d = __builtin_amdgcn_mfma_f32_16x16x32_bf16(afm, bfw, d, 0, 0, 0);
            }
            float bgv = bg[c0 + lr];
            if (s < 2) {
                unsigned short p[4];
                #pragma unroll
                for (int i = 0; i < 4; ++i) {
                    int ii = i0 + ks * 4 + i;
                    p[i] = f2bf(fmaxf(d[i] + bgv, 0.f) * snorm[ii]);
                }
                *(uint2*)(&hsT[c0 + lr][i0 + ks * 4]) = *(uint2*)p;
            } else {
                #pragma unroll
                for (int i = 0; i < 4; ++i)
                    tp[ct][i] = f2bf(tanhf(d[i] + bgv));
            }
        }
        if (s < 2) {
            __syncthreads();           // hsT fully rewritten before next mm1
        } else {
            // write tanh-h into ms rows (wave-private; mm2 reads of ms done)
            #pragma unroll
            for (int ct = 0; ct < 8; ++ct)
                #pragma unroll
                for (int i = 0; i < 4; ++i)
                    ms[i0 + ks * 4 + i][ct * 16 + lr] = tp[ct][i];
        }
    }

    // hW1 = tanh-h @ W1_top + b1c  (A rows wave-private in ms)
    short8 ah[4];
    #pragma unroll
    for (int kk = 0; kk < 4; ++kk)
        ah[kk] = *(const short8*)(&ms[i0 + lr][kk * 32 + lk]);
    #pragma unroll
    for (int jjt = 0; jjt < 12; ++jjt) {
        int jj0 = jjt * 16;
        f32x4 d = {0.f, 0.f, 0.f, 0.f};
        #pragma unroll
        for (int kk = 0; kk < 4; ++kk) {
            short8 bfw = *(const short8*)(W1tT + (size_t)(jj0 + lr) * CG + kk * 32 + lk);
            d = __builtin_amdgcn_mfma_f32_16x16x32_bf16(ah[kk], bfw, d, 0, 0, 0);
        }
        float bv = b1c[jj0 + lr];
        #pragma unroll
        for (int i = 0; i < 4; ++i)
            hW1[((size_t)b * NN + i0 + ks * 4 + i) * HID + jj0 + lr] = d[i] + bv;
    }
}

// ---------------------------------------------------------------------------
// K4: acc[b] += sum_{n,l} v . relu(hW1[b,n,:] + rWa[b,l,:] + rWb[b,l,:])
//     last block writes out[b] = acc[b] + cconst.
// grid 512 x 256
// ---------------------------------------------------------------------------
__global__ __launch_bounds__(256) void k4_pairsum(
    const float* __restrict__ hW1, const float* __restrict__ rWa,
    const float* __restrict__ rWb,
    const float* __restrict__ vbuf, float* __restrict__ acc,
    const float* __restrict__ cconst, unsigned* __restrict__ ctr,
    float* __restrict__ out)
{
    int t = threadIdx.x;
    int blk = blockIdx.x;
    int b = blk >> 6;
    int ns = (blk >> 3) & 7;
    int lt = blk & 7;
    int wv = t >> 6;
    int lane = t & 63;
    int j0 = wv * 48;
    int l = lt * 64 + lane;
    float r[48], v[48];
    const float* rpa = rWa + ((size_t)b * LL + l) * HID + j0;
    const float* rpb = rWb + ((size_t)b * LL + l) * HID + j0;
    const float* vp = vbuf + j0;
    #pragma unroll
    for (int q = 0; q < 12; ++q) {
        float4 f = *(const float4*)(rpa + q * 4);
        float4 g = *(const float4*)(rpb + q * 4);
        r[q * 4 + 0] = f.x + g.x; r[q * 4 + 1] = f.y + g.y;
        r[q * 4 + 2] = f.z + g.z; r[q * 4 + 3] = f.w + g.w;
    }
    #pragma unroll
    for (int q = 0; q < 12; ++q) {
        float4 f = *(const float4*)(vp + q * 4);
        v[q * 4 + 0] = f.x; v[q * 4 + 1] = f.y; v[q * 4 + 2] = f.z; v[q * 4 + 3] = f.w;
    }
    float a0 = 0.f, a1 = 0.f, a2 = 0.f, a3 = 0.f;
    const float* hp = hW1 + ((size_t)b * NN + ns * 16) * HID + j0;
    for (int n = 0; n < 16; ++n) {
        float hv[48];
        #pragma unroll
        for (int q = 0; q < 12; ++q) {
            float4 f = *(const float4*)(hp + n * HID + q * 4);
            hv[q * 4 + 0] = f.x; hv[q * 4 + 1] = f.y; hv[q * 4 + 2] = f.z; hv[q * 4 + 3] = f.w;
        }
        #pragma unroll
        for (int j = 0; j < 48; j += 4) {
            a0 = fmaf(v[j + 0], fmaxf(hv[j + 0] + r[j + 0], 0.f), a0);
            a1 = fmaf(v[j + 1], fmaxf(hv[j + 1] + r[j + 1], 0.f), a1);
            a2 = fmaf(v[j + 2], fmaxf(hv[j + 2] + r[j + 2], 0.f), a2);
            a3 = fmaf(v[j + 3], fmaxf(hv[j + 3] + r[j + 3], 0.f), a3);
        }
    }
    float a = (a0 + a1) + (a2 + a3);
    for (int off = 32; off; off >>= 1) a += __shfl_down(a, off);
    __shared__ float sred[4];
    __shared__ int lastf;
    if (lane == 0) sred[wv] = a;
    __syncthreads();
    if (t == 0) {
        atomicAdd(&acc[b], (sred[0] + sred[1]) + (sred[2] + sred[3]));
        __threadfence();
        unsigned old = atomicAdd(ctr, 1u);
        lastf = (old == gridDim.x - 1) ? 1 : 0;
    }
    __syncthreads();
    if (lastf && t < BB)
        out[t] = atomicAdd(&acc[t], 0.0f) + cconst[0];
}

extern "C" void kernel_launch(void* const* d_in, const int* in_sizes, int n_in,
                              void* d_out, int out_size, void* d_ws, size_t ws_size,
                              hipStream_t stream)
{
    const float* adj   = (const float*)d_in[0];
    const float* nodes = (const float*)d_in[1];
    const float* prot  = (const float*)d_in[2];
    const float* Wn    = (const float*)d_in[3];
    const float* bn    = (const float*)d_in[4];
    const float* Wg    = (const float*)d_in[5];
    const float* bg    = (const float*)d_in[6];
    const float* Wr    = (const float*)d_in[7];
    const float* br    = (const float*)d_in[8];
    // d_in[9]=Wa, d_in[10]=ba: unused (softmax over size-1 axis == 1)
    const float* W1    = (const float*)d_in[11];
    const float* b1    = (const float*)d_in[12];
    const float* W2    = (const float*)d_in[13];
    const float* b2    = (const float*)d_in[14];
    const float* Wo    = (const float*)d_in[15];
    const float* bo    = (const float*)d_in[16];

    float* ws     = (float*)d_ws;
    float* hA     = ws;                        // [8][128][128]
    float* normb  = ws + 131072;               // [8][128]
    float* hW1b   = ws + 132096;               // [8][128][192]
    float* rWp    = ws + 328704;               // 2 x [4096][192]
    float* vbuf   = ws + 1901568;              // [192]
    float* cconst = ws + 1901760;              // [1]
    float* accb   = ws + 1901764;              // [8]
    float* b1c    = ws + 1901772;              // [192]
    unsigned* ctr = (unsigned*)(ws + 1901964); // [1]
    unsigned short* protb = (unsigned short*)(ws + 1901968); // [4096][1024]
    unsigned short* WcT   = (unsigned short*)(ws + 3999120); // [192][1024]
    unsigned short* adjb  = (unsigned short*)(ws + 4097424); // [8][128][128]
    unsigned short* WgT   = (unsigned short*)(ws + 4162960); // [128][128]
    unsigned short* W1tT  = (unsigned short*)(ws + 4171152); // [192][128]
    float* out    = (float*)d_out;

    hipLaunchKernelGGL(k1_prep, dim3(2563), dim3(256), 0, stream,
                       adj, nodes, prot, Wn, bn, Wr, br, W1, b1, Wg, W2, b2, Wo, bo,
                       hA, normb, vbuf, cconst, accb, ctr, WcT, b1c, protb,
                       adjb, WgT, W1tT);
    hipLaunchKernelGGL(kmid, dim3(264), dim3(512), 0, stream,
                       protb, WcT, rWp, adjb, WgT, W1tT, bg, normb, hA, b1c, hW1b);
    hipLaunchKernelGGL(k4_pairsum, dim3(512), dim3(256), 0, stream,
                       hW1b, rWp, rWp + 786432, vbuf, accb, cconst, ctr, out);
}